// Round 6
// baseline (655.049 us; speedup 1.0000x reference)
//
#include <hip/hip_runtime.h>
#include <hip/hip_bf16.h>

#define Sdim 4096
#define Ndim 32
#define Hdim 512
#define Mdim (Sdim * 32)

typedef __bf16 bf16x8 __attribute__((ext_vector_type(8)));
typedef float f32x4 __attribute__((ext_vector_type(4)));
typedef unsigned short ushort8v __attribute__((ext_vector_type(8)));

__device__ __forceinline__ void load_lds16(const void* g, void* l) {
    __builtin_amdgcn_global_load_lds(
        (const __attribute__((address_space(1))) void*)g,
        (__attribute__((address_space(3))) void*)l, 16, 0, 0);
}

__device__ __forceinline__ float ftanh(float x) {
    float e = __expf(2.f * x);
    return 1.f - 2.f / (e + 1.f);
}

// ---------------- bias_t[c][n] = hidden[n]·Ww[c] + Wb[c] + Ub[c]
__global__ __launch_bounds__(256) void k_prep_bias(
    const float* __restrict__ hidden, const float* __restrict__ Ww,
    const float* __restrict__ Wb, const float* __restrict__ Ubias,
    float* __restrict__ bias_t) {  // [H][N]
    const int t = threadIdx.x, w = t >> 6, lane = t & 63;
    const int cc = blockIdx.x * 4 + w;
    const float4 w0 = *(const float4*)(Ww + (size_t)cc * Hdim + lane * 8);
    const float4 w1 = *(const float4*)(Ww + (size_t)cc * Hdim + lane * 8 + 4);
    const float wb = Wb[cc] + Ubias[cc];
    for (int n = 0; n < Ndim; ++n) {
        const float4 h0 = *(const float4*)(hidden + n * Hdim + lane * 8);
        const float4 h1 = *(const float4*)(hidden + n * Hdim + lane * 8 + 4);
        float p = w0.x * h0.x + w0.y * h0.y + w0.z * h0.z + w0.w * h0.w +
                  w1.x * h1.x + w1.y * h1.y + w1.z * h1.z + w1.w * h1.w;
        p += __shfl_xor(p, 1);  p += __shfl_xor(p, 2);
        p += __shfl_xor(p, 4);  p += __shfl_xor(p, 8);
        p += __shfl_xor(p, 16); p += __shfl_xor(p, 32);
        if (lane == 0) bias_t[cc * Ndim + n] = p + wb;
    }
}

// ---------------- U_w fp32 -> bf16
__global__ __launch_bounds__(256) void k_cvt(
    const float* __restrict__ src, unsigned short* __restrict__ dst) {
    const int i = blockIdx.x * 256 + threadIdx.x;
    float4 v = ((const float4*)src)[i];
    union { __hip_bfloat162 h[2]; ushort4 u; } r;
    r.h[0] = __float22bfloat162_rn(make_float2(v.x, v.y));
    r.h[1] = __float22bfloat162_rn(make_float2(v.z, v.w));
    ((ushort4*)dst)[i] = r.u;
}

// ---------------- enc fp32 -> bf16 (streaming, 8 elems/thread)
__global__ __launch_bounds__(256) void k_cvt_enc(
    const float* __restrict__ src, unsigned short* __restrict__ dst) {
    const size_t i = (size_t)blockIdx.x * 256 + threadIdx.x;
    const float4 a = ((const float4*)src)[2 * i];
    const float4 b = ((const float4*)src)[2 * i + 1];
    union { __hip_bfloat162 h[4]; ushort8v v; } r;
    r.h[0] = __float22bfloat162_rn(make_float2(a.x, a.y));
    r.h[1] = __float22bfloat162_rn(make_float2(a.z, a.w));
    r.h[2] = __float22bfloat162_rn(make_float2(b.x, b.y));
    r.h[3] = __float22bfloat162_rn(make_float2(b.z, b.w));
    ((ushort8v*)dst)[i] = r.v;
}

// ---------------- m97-clone fused score GEMM.
// Tile 128M x 256N, BK=64, 512 thr / 8 waves (2 wM x 4 wN), wave 64x64.
// A (encb bf16) and B (Ub bf16) both staged via global_load_lds width=16.
// XOR swizzle: LDS slot s of row r holds global 16B-chunk s^(r&7) -> all
// b128 reads are exact 2-way bank aliases (free, m136).
__global__ __launch_bounds__(512, 3) void k_gemm_score(
    const unsigned short* __restrict__ encb,  // [M][512] bf16
    const unsigned short* __restrict__ Ub,    // [512][512] bf16
    const float* __restrict__ bias_t,         // [H][N]
    const float* __restrict__ vw,             // [H]
    float* __restrict__ scorep) {             // [2][N][S] partials
    __shared__ __align__(16) unsigned short Asm[128 * 64];  // 16 KB
    __shared__ __align__(16) unsigned short Bsm[256 * 64];  // 32 KB
    __shared__ float ssm[4][128];

    const int t = threadIdx.x;
    const int lane = t & 63;
    const int w = t >> 6;      // 0..7
    const int wM = w >> 2;     // 0..1
    const int wN = w & 3;      // 0..3
    const int c = lane & 15;
    const int q = lane >> 4;

    const int rowblk = blockIdx.x >> 1;
    const int colblk = blockIdx.x & 1;
    const int mBase = rowblk * 128;
    const int colBase = colblk * 256;

    // DMA: 1 KB/instr = 8 rows x 128B. Lane l -> row j*8+(l>>3), slot l&7,
    // fetching global chunk (l&7)^((l>>3)&7).
    const int l3 = lane >> 3;
    const int gch = (lane & 7) ^ (l3 & 7);
    const unsigned short* aSrc[2];
    unsigned short* aDst[2];
#pragma unroll
    for (int i = 0; i < 2; ++i) {
        const int j = 2 * w + i;  // A instr 0..15 -> rows j*8..j*8+7
        aSrc[i] = encb + (size_t)(mBase + j * 8 + l3) * Hdim + gch * 8;
        aDst[i] = &Asm[j * 8 * 64];
    }
    const unsigned short* bSrc[4];
    unsigned short* bDst[4];
#pragma unroll
    for (int i = 0; i < 4; ++i) {
        const int j = 4 * w + i;  // B instr 0..31 -> cols j*8..j*8+7
        bSrc[i] = Ub + (size_t)(colBase + j * 8 + l3) * Hdim + gch * 8;
        bDst[i] = &Bsm[j * 8 * 64];
    }

    f32x4 acc[4][4];
#pragma unroll
    for (int i = 0; i < 4; ++i)
#pragma unroll
        for (int j = 0; j < 4; ++j) acc[i][j] = (f32x4){0.f, 0.f, 0.f, 0.f};

#pragma unroll
    for (int kk = 0; kk < 8; ++kk) {
        __syncthreads();  // prev ds_reads done -> LDS reusable
        load_lds16(aSrc[0] + kk * 64, aDst[0]);
        load_lds16(aSrc[1] + kk * 64, aDst[1]);
#pragma unroll
        for (int i = 0; i < 4; ++i)
            load_lds16(bSrc[i] + kk * 64, bDst[i]);
        __syncthreads();  // DMA drained -> LDS valid

#pragma unroll
        for (int kh = 0; kh < 2; ++kh) {
            bf16x8 af[4], bfr[4];
            const int slot = (kh * 4 + q) ^ (c & 7);
#pragma unroll
            for (int mi = 0; mi < 4; ++mi) {
                const int r = wM * 64 + mi * 16 + c;
                af[mi] = *(const bf16x8*)&Asm[r * 64 + slot * 8];
            }
#pragma unroll
            for (int ni = 0; ni < 4; ++ni) {
                const int r = wN * 64 + ni * 16 + c;
                bfr[ni] = *(const bf16x8*)&Bsm[r * 64 + slot * 8];
            }
#pragma unroll
            for (int mi = 0; mi < 4; ++mi)
#pragma unroll
                for (int ni = 0; ni < 4; ++ni)
                    acc[mi][ni] = __builtin_amdgcn_mfma_f32_16x16x32_bf16(
                        af[mi], bfr[ni], acc[mi][ni], 0, 0, 0);
        }
    }

    // epilogue: partial score = sum_col v[col]*tanh(acc + bias) (v_b cancels)
    float vcol[4];
#pragma unroll
    for (int ni = 0; ni < 4; ++ni)
        vcol[ni] = vw[colBase + wN * 64 + ni * 16 + c];

#pragma unroll
    for (int mi = 0; mi < 4; ++mi) {
#pragma unroll
        for (int reg = 0; reg < 4; ++reg) {
            const int rl = wM * 64 + mi * 16 + q * 4 + reg;  // 0..127
            const int n = rl & 31;                           // mBase%128==0
            float p = 0.f;
#pragma unroll
            for (int ni = 0; ni < 4; ++ni) {
                const int col = colBase + wN * 64 + ni * 16 + c;
                float e = acc[mi][ni][reg] + bias_t[col * Ndim + n];
                p += vcol[ni] * ftanh(e);
            }
            p += __shfl_xor(p, 1);
            p += __shfl_xor(p, 2);
            p += __shfl_xor(p, 4);
            p += __shfl_xor(p, 8);
            if (c == 0) ssm[wN][rl] = p;
        }
    }
    __syncthreads();
    if (t < 128) {
        const int m = mBase + t;
        const float s = ssm[0][t] + ssm[1][t] + ssm[2][t] + ssm[3][t];
        scorep[colblk * Mdim + (m & 31) * Sdim + (m >> 5)] = s;
    }
}

// ---------------- FALLBACK gemm (enc fp32 in-loop cvt) if ws too small — R5.
__global__ __launch_bounds__(256, 3) void k_gemm_score_fb(
    const float* __restrict__ enc, const unsigned short* __restrict__ Ub,
    const float* __restrict__ bias_t, const float* __restrict__ vw,
    float* __restrict__ scorep) {
    __shared__ __align__(16) unsigned short Asm[64 * 72];
    __shared__ __align__(16) unsigned short Bsm[256 * 64];
    __shared__ float ssm[4][64];
    const int t = threadIdx.x, lane = t & 63, w = t >> 6;
    const int c = lane & 15, q = lane >> 4;
    const int rowblk = blockIdx.x >> 1, colblk = blockIdx.x & 1;
    const int mBase = rowblk * 64, colBase = colblk * 256;
    const int ar = t >> 2, aq = t & 3;
    const float* aptr = enc + (size_t)(mBase + ar) * Hdim + aq * 16;
    unsigned short* awr = &Asm[ar * 72 + aq * 16];
    const int brow = lane >> 3;
    const int gchunk = (lane & 7) ^ (brow & 7);
    const unsigned short* bptr[8];
    unsigned short* bdst[8];
#pragma unroll
    for (int j = 0; j < 8; ++j) {
        const int r0 = w * 64 + j * 8;
        bptr[j] = Ub + (size_t)(colBase + r0 + brow) * Hdim + gchunk * 8;
        bdst[j] = &Bsm[r0 * 64];
    }
    f32x4 acc[4][4];
#pragma unroll
    for (int i = 0; i < 4; ++i)
#pragma unroll
        for (int j = 0; j < 4; ++j) acc[i][j] = (f32x4){0.f, 0.f, 0.f, 0.f};
    float4 pa0 = *(const float4*)(aptr + 0), pa1 = *(const float4*)(aptr + 4);
    float4 pa2 = *(const float4*)(aptr + 8), pa3 = *(const float4*)(aptr + 12);
#pragma unroll
    for (int kk = 0; kk < 8; ++kk) {
        __syncthreads();
        union { __hip_bfloat162 h[4]; bf16x8 v; } p0, p1;
        p0.h[0] = __float22bfloat162_rn(make_float2(pa0.x, pa0.y));
        p0.h[1] = __float22bfloat162_rn(make_float2(pa0.z, pa0.w));
        p0.h[2] = __float22bfloat162_rn(make_float2(pa1.x, pa1.y));
        p0.h[3] = __float22bfloat162_rn(make_float2(pa1.z, pa1.w));
        p1.h[0] = __float22bfloat162_rn(make_float2(pa2.x, pa2.y));
        p1.h[1] = __float22bfloat162_rn(make_float2(pa2.z, pa2.w));
        p1.h[2] = __float22bfloat162_rn(make_float2(pa3.x, pa3.y));
        p1.h[3] = __float22bfloat162_rn(make_float2(pa3.z, pa3.w));
        *(bf16x8*)(awr) = p0.v;
        *(bf16x8*)(awr + 8) = p1.v;
#pragma unroll
        for (int j = 0; j < 8; ++j) load_lds16(bptr[j] + kk * 64, bdst[j]);
        __syncthreads();
        if (kk < 7) {
            pa0 = *(const float4*)(aptr + (kk + 1) * 64);
            pa1 = *(const float4*)(aptr + (kk + 1) * 64 + 4);
            pa2 = *(const float4*)(aptr + (kk + 1) * 64 + 8);
            pa3 = *(const float4*)(aptr + (kk + 1) * 64 + 12);
        }
#pragma unroll
        for (int kh = 0; kh < 2; ++kh) {
            bf16x8 af[4], bfr[4];
#pragma unroll
            for (int mi = 0; mi < 4; ++mi)
                af[mi] = *(const bf16x8*)&Asm[(mi * 16 + c) * 72 + kh * 32 + q * 8];
#pragma unroll
            for (int ni = 0; ni < 4; ++ni) {
                const int r = w * 64 + ni * 16 + c;
                const int slot = (kh * 4 + q) ^ (c & 7);
                bfr[ni] = *(const bf16x8*)&Bsm[r * 64 + slot * 8];
            }
#pragma unroll
            for (int mi = 0; mi < 4; ++mi)
#pragma unroll
                for (int ni = 0; ni < 4; ++ni)
                    acc[mi][ni] = __builtin_amdgcn_mfma_f32_16x16x32_bf16(
                        af[mi], bfr[ni], acc[mi][ni], 0, 0, 0);
        }
    }
    float vcol[4];
#pragma unroll
    for (int ni = 0; ni < 4; ++ni) vcol[ni] = vw[colBase + w * 64 + ni * 16 + c];
#pragma unroll
    for (int mi = 0; mi < 4; ++mi) {
#pragma unroll
        for (int reg = 0; reg < 4; ++reg) {
            const int rl = mi * 16 + q * 4 + reg;
            const int n = rl & 31;
            float p = 0.f;
#pragma unroll
            for (int ni = 0; ni < 4; ++ni) {
                const int col = colBase + w * 64 + ni * 16 + c;
                float e = acc[mi][ni][reg] + bias_t[col * Ndim + n];
                p += vcol[ni] * ftanh(e);
            }
            p += __shfl_xor(p, 1);
            p += __shfl_xor(p, 2);
            p += __shfl_xor(p, 4);
            p += __shfl_xor(p, 8);
            if (c == 0) ssm[w][rl] = p;
        }
    }
    __syncthreads();
    if (t < 64) {
        const int m = mBase + t;
        const float s = ssm[0][t] + ssm[1][t] + ssm[2][t] + ssm[3][t];
        scorep[colblk * Mdim + (m & 31) * Sdim + (m >> 5)] = s;
    }
}

// ---------------- softmax over S per n; coalesced write to wts [N][S]
__global__ __launch_bounds__(256) void k_softmax(
    const float* __restrict__ scorep, float* __restrict__ wts) {
    const int n = blockIdx.x;
    const int t = threadIdx.x;
    const int w = t >> 6;
    __shared__ float row[Sdim];
    __shared__ float red[8];
    const float4* s0 = (const float4*)(scorep + n * Sdim);
    const float4* s1 = (const float4*)(scorep + Mdim + n * Sdim);
    float mx = -1e30f;
    for (int i = t; i < Sdim / 4; i += 256) {
        float4 a = s0[i], b = s1[i];
        float4 v;
        v.x = a.x + b.x; v.y = a.y + b.y; v.z = a.z + b.z; v.w = a.w + b.w;
        ((float4*)row)[i] = v;
        mx = fmaxf(mx, fmaxf(fmaxf(v.x, v.y), fmaxf(v.z, v.w)));
    }
#pragma unroll
    for (int o = 32; o > 0; o >>= 1) mx = fmaxf(mx, __shfl_xor(mx, o));
    if ((t & 63) == 0) red[w] = mx;
    __syncthreads();
    mx = fmaxf(fmaxf(red[0], red[1]), fmaxf(red[2], red[3]));
    float sum = 0.f;
    for (int i = t; i < Sdim; i += 256) sum += __expf(row[i] - mx);
#pragma unroll
    for (int o = 32; o > 0; o >>= 1) sum += __shfl_xor(sum, o);
    if ((t & 63) == 0) red[4 + w] = sum;
    __syncthreads();
    sum = red[4] + red[5] + red[6] + red[7];
    const float inv = 1.f / sum;
    for (int i = t; i < Sdim; i += 256)
        wts[n * Sdim + i] = __expf(row[i] - mx) * inv;
}

// ---------------- wts [N][S] -> out_w [S][N]
__global__ __launch_bounds__(256) void k_transpose(
    const float* __restrict__ wts, float* __restrict__ out_w) {
    __shared__ float tl[Ndim][129];
    const int s0 = blockIdx.x * 128;
    const int t = threadIdx.x;
    const int rr = t >> 3, cb = (t & 7) * 4;
#pragma unroll
    for (int j = 0; j < 4; ++j)
        *(float4*)&tl[rr][cb + j * 32] =
            *(const float4*)(wts + (size_t)rr * Sdim + s0 + cb + j * 32);
    __syncthreads();
    const int sl = t >> 1, nb = (t & 1) * 16;
#pragma unroll
    for (int j = 0; j < 4; ++j) {
        const int n0 = nb + j * 4;
        float4 v;
        v.x = tl[n0][sl]; v.y = tl[n0 + 1][sl];
        v.z = tl[n0 + 2][sl]; v.w = tl[n0 + 3][sl];
        *(float4*)(out_w + (size_t)(s0 + sl) * Ndim + n0) = v;
    }
}

// ---------------- context partials over 128-s chunks
__global__ __launch_bounds__(256) void k_context(
    const float* __restrict__ enc, const float* __restrict__ wts,
    float* __restrict__ part) {
    const int n = blockIdx.x & 31;
    const int sc = blockIdx.x >> 5;
    const int s0 = sc * 128;
    const int t = threadIdx.x;
    const int hv = t & 127;
    const int sl = t >> 7;
    const float* wrow = wts + (size_t)n * Sdim + s0;
    float4 a0 = {0, 0, 0, 0}, a1 = {0, 0, 0, 0};
    float4 a2 = {0, 0, 0, 0}, a3 = {0, 0, 0, 0};
    for (int i = sl * 4; i < 128; i += 8) {
        const float w0 = wrow[i], w1 = wrow[i + 1];
        const float w2 = wrow[i + 2], w3 = wrow[i + 3];
        const float4 e0 = *(const float4*)(enc + ((size_t)(s0 + i) * Ndim + n) * Hdim + hv * 4);
        const float4 e1 = *(const float4*)(enc + ((size_t)(s0 + i + 1) * Ndim + n) * Hdim + hv * 4);
        const float4 e2 = *(const float4*)(enc + ((size_t)(s0 + i + 2) * Ndim + n) * Hdim + hv * 4);
        const float4 e3 = *(const float4*)(enc + ((size_t)(s0 + i + 3) * Ndim + n) * Hdim + hv * 4);
        a0.x += w0 * e0.x; a0.y += w0 * e0.y; a0.z += w0 * e0.z; a0.w += w0 * e0.w;
        a1.x += w1 * e1.x; a1.y += w1 * e1.y; a1.z += w1 * e1.z; a1.w += w1 * e1.w;
        a2.x += w2 * e2.x; a2.y += w2 * e2.y; a2.z += w2 * e2.z; a2.w += w2 * e2.w;
        a3.x += w3 * e3.x; a3.y += w3 * e3.y; a3.z += w3 * e3.z; a3.w += w3 * e3.w;
    }
    a0.x += a1.x + a2.x + a3.x; a0.y += a1.y + a2.y + a3.y;
    a0.z += a1.z + a2.z + a3.z; a0.w += a1.w + a2.w + a3.w;
    __shared__ float4 red[128];
    if (sl == 1) red[hv] = a0;
    __syncthreads();
    if (sl == 0) {
        const float4 b = red[hv];
        float4 r;
        r.x = a0.x + b.x; r.y = a0.y + b.y; r.z = a0.z + b.z; r.w = a0.w + b.w;
        *(float4*)(part + (size_t)(sc * 32 + n) * Hdim + hv * 4) = r;
    }
}

__global__ __launch_bounds__(256) void k_ctx_reduce(
    const float* __restrict__ part, float* __restrict__ out) {
    const int j = blockIdx.x * 256 + threadIdx.x;
    float4 s = {0, 0, 0, 0};
    for (int i = 0; i < 32; ++i) {
        const float4 v = ((const float4*)part)[i * 4096 + j];
        s.x += v.x; s.y += v.y; s.z += v.z; s.w += v.w;
    }
    ((float4*)out)[j] = s;
}

extern "C" void kernel_launch(void* const* d_in, const int* in_sizes, int n_in,
                              void* d_out, int out_size, void* d_ws,
                              size_t ws_size, hipStream_t stream) {
    const float* hidden = (const float*)d_in[0];
    const float* enc    = (const float*)d_in[1];
    const float* Ww     = (const float*)d_in[2];
    const float* Wb     = (const float*)d_in[3];
    const float* Uw     = (const float*)d_in[4];
    const float* Ubias  = (const float*)d_in[5];
    const float* vw     = (const float*)d_in[6];

    float* out = (float*)d_out;  // [0,16384): context; rest: weights [S][N]

    char* ws = (char*)d_ws;
    unsigned short* Ub16 = (unsigned short*)(ws);                // 512 KB
    float* bias_t        = (float*)(ws + (512 << 10));           // 64 KB
    float* scorep        = (float*)(ws + (576 << 10));           // 1 MB
    float* wts           = (float*)(ws + (1600 << 10));          // 512 KB
    float* part          = (float*)(ws + (2112 << 10));          // 2 MB
    unsigned short* encb = (unsigned short*)(ws + (8 << 20));    // 128 MB
    const size_t REQ = (8ull << 20) + (size_t)Mdim * Hdim * 2;

    k_prep_bias<<<128, 256, 0, stream>>>(hidden, Ww, Wb, Ubias, bias_t);
    k_cvt<<<256, 256, 0, stream>>>(Uw, Ub16);
    if (ws_size >= REQ) {
        k_cvt_enc<<<32768, 256, 0, stream>>>(enc, encb);
        k_gemm_score<<<(Mdim / 128) * 2, 512, 0, stream>>>(encb, Ub16, bias_t,
                                                           vw, scorep);
    } else {
        k_gemm_score_fb<<<(Mdim / 64) * 2, 256, 0, stream>>>(enc, Ub16, bias_t,
                                                             vw, scorep);
    }
    k_softmax<<<Ndim, 256, 0, stream>>>(scorep, wts);
    k_transpose<<<Sdim / 128, 256, 0, stream>>>(wts, out + Ndim * Hdim);
    k_context<<<Ndim * (Sdim / 128), 256, 0, stream>>>(enc, wts, part);
    k_ctx_reduce<<<16, 256, 0, stream>>>(part, out);
}

// Round 7
// 650.019 us; speedup vs baseline: 1.0077x; 1.0077x over previous
//
#include <hip/hip_runtime.h>
#include <hip/hip_bf16.h>

#define Sdim 4096
#define Ndim 32
#define Hdim 512
#define Mdim (Sdim * 32)

typedef __bf16 bf16x8 __attribute__((ext_vector_type(8)));
typedef float f32x4 __attribute__((ext_vector_type(4)));
typedef unsigned short ushort8v __attribute__((ext_vector_type(8)));

__device__ __forceinline__ void load_lds16(const void* g, void* l) {
    __builtin_amdgcn_global_load_lds(
        (const __attribute__((address_space(1))) void*)g,
        (__attribute__((address_space(3))) void*)l, 16, 0, 0);
}

__device__ __forceinline__ float ftanh(float x) {
    float e = __expf(2.f * x);
    return 1.f - 2.f / (e + 1.f);
}

// ---------------- merged prep: blocks 0..127 -> bias_t; 128..383 -> Uw cvt
__global__ __launch_bounds__(256) void k_prep(
    const float* __restrict__ hidden, const float* __restrict__ Ww,
    const float* __restrict__ Wb, const float* __restrict__ Ubias,
    const float* __restrict__ Uw, float* __restrict__ bias_t,  // [H][N]
    unsigned short* __restrict__ Ub16) {
    if (blockIdx.x < 128) {
        const int t = threadIdx.x, w = t >> 6, lane = t & 63;
        const int cc = blockIdx.x * 4 + w;
        const float4 w0 = *(const float4*)(Ww + (size_t)cc * Hdim + lane * 8);
        const float4 w1 = *(const float4*)(Ww + (size_t)cc * Hdim + lane * 8 + 4);
        const float wb = Wb[cc] + Ubias[cc];
        for (int n = 0; n < Ndim; ++n) {
            const float4 h0 = *(const float4*)(hidden + n * Hdim + lane * 8);
            const float4 h1 = *(const float4*)(hidden + n * Hdim + lane * 8 + 4);
            float p = w0.x * h0.x + w0.y * h0.y + w0.z * h0.z + w0.w * h0.w +
                      w1.x * h1.x + w1.y * h1.y + w1.z * h1.z + w1.w * h1.w;
            p += __shfl_xor(p, 1);  p += __shfl_xor(p, 2);
            p += __shfl_xor(p, 4);  p += __shfl_xor(p, 8);
            p += __shfl_xor(p, 16); p += __shfl_xor(p, 32);
            if (lane == 0) bias_t[cc * Ndim + n] = p + wb;
        }
    } else {
        const int i = (blockIdx.x - 128) * 256 + threadIdx.x;
        float4 v = ((const float4*)Uw)[i];
        union { __hip_bfloat162 h[2]; ushort4 u; } r;
        r.h[0] = __float22bfloat162_rn(make_float2(v.x, v.y));
        r.h[1] = __float22bfloat162_rn(make_float2(v.z, v.w));
        ((ushort4*)Ub16)[i] = r.u;
    }
}

// ---------------- enc fp32 -> bf16 (streaming)
__global__ __launch_bounds__(256) void k_cvt_enc(
    const float* __restrict__ src, unsigned short* __restrict__ dst) {
    const size_t i = (size_t)blockIdx.x * 256 + threadIdx.x;
    const float4 a = ((const float4*)src)[2 * i];
    const float4 b = ((const float4*)src)[2 * i + 1];
    union { __hip_bfloat162 h[4]; ushort8v v; } r;
    r.h[0] = __float22bfloat162_rn(make_float2(a.x, a.y));
    r.h[1] = __float22bfloat162_rn(make_float2(a.z, a.w));
    r.h[2] = __float22bfloat162_rn(make_float2(b.x, b.y));
    r.h[3] = __float22bfloat162_rn(make_float2(b.z, b.w));
    ((ushort8v*)dst)[i] = r.v;
}

// ---------------- persistent-B fused score GEMM.
// Block = 512 thr / 8 waves, owns a 128-col B strip (128 KB dynamic LDS,
// loaded once, 1 barrier). Then 4 panels x 256 rows: K-loop has ZERO
// barriers — A bf16 frags stream from global with explicit next-step
// register rotation; B via ds_read_b128, XOR-swizzled (0 conflicts, R6).
// Wave = 64 rows (wM=w>>1) x 64 cols (wN=w&1). Epilogue: tanh + v-dot.
__global__ __launch_bounds__(512, 2) void k_gemm_score(
    const unsigned short* __restrict__ encb,  // [M][H] bf16
    const unsigned short* __restrict__ Ub,    // [H][H] bf16
    const float* __restrict__ bias_t,         // [H][N]
    const float* __restrict__ vw,             // [H]
    float* __restrict__ scorep) {             // [4][N][S] strip partials
    extern __shared__ __align__(16) unsigned short Bsm[];  // [128][512]
    __shared__ float ssm[2][256];

    const int t = threadIdx.x;
    const int lane = t & 63;
    const int w = t >> 6;    // 0..7
    const int wM = w >> 1;   // 0..3 -> row group
    const int wN = w & 1;    // 0..1 -> col half
    const int c = lane & 15;
    const int q = lane >> 4;

    const int strip = blockIdx.x & 3;
    const int bgroup = blockIdx.x >> 2;  // 0..127
    const int colBase = strip * 128;

    // B strip load: wave w loads cols w*16..+15; one column = one 1KB DMA.
    // LDS slot s of col holds global 16B-chunk s^(col&7).
#pragma unroll
    for (int j = 0; j < 16; ++j) {
        const int col = w * 16 + j;
        const unsigned short* src =
            Ub + (size_t)(colBase + col) * Hdim + (lane ^ (col & 7)) * 8;
        load_lds16(src, &Bsm[col * Hdim]);
    }

    float vcol[4];
#pragma unroll
    for (int ni = 0; ni < 4; ++ni)
        vcol[ni] = vw[colBase + wN * 64 + ni * 16 + c];

    __syncthreads();  // B strip resident for block lifetime

    for (int p = 0; p < 4; ++p) {
        const int rowBase = (bgroup + p * 128) * 256;
        const unsigned short* aRow[4];
#pragma unroll
        for (int mi = 0; mi < 4; ++mi)
            aRow[mi] =
                encb + (size_t)(rowBase + wM * 64 + mi * 16 + c) * Hdim + q * 8;

        f32x4 acc[4][4];
#pragma unroll
        for (int i = 0; i < 4; ++i)
#pragma unroll
            for (int j = 0; j < 4; ++j) acc[i][j] = (f32x4){0.f, 0.f, 0.f, 0.f};

        bf16x8 aC[4][2];
#pragma unroll
        for (int mi = 0; mi < 4; ++mi)
#pragma unroll
            for (int kh = 0; kh < 2; ++kh)
                aC[mi][kh] = *(const bf16x8*)(aRow[mi] + kh * 32);

#pragma unroll
        for (int kk = 0; kk < 8; ++kk) {
            bf16x8 aN[4][2];
            if (kk < 7) {
#pragma unroll
                for (int mi = 0; mi < 4; ++mi)
#pragma unroll
                    for (int kh = 0; kh < 2; ++kh)
                        aN[mi][kh] = *(const bf16x8*)(aRow[mi] +
                                                      (kk + 1) * 64 + kh * 32);
            }
#pragma unroll
            for (int kh = 0; kh < 2; ++kh) {
                bf16x8 bfr[4];
#pragma unroll
                for (int ni = 0; ni < 4; ++ni) {
                    const int col = wN * 64 + ni * 16 + c;
                    const int slot = kk * 8 + ((kh * 4 + q) ^ (col & 7));
                    bfr[ni] = *(const bf16x8*)&Bsm[col * Hdim + slot * 8];
                }
#pragma unroll
                for (int mi = 0; mi < 4; ++mi)
#pragma unroll
                    for (int ni = 0; ni < 4; ++ni)
                        acc[mi][ni] = __builtin_amdgcn_mfma_f32_16x16x32_bf16(
                            aC[mi][kh], bfr[ni], acc[mi][ni], 0, 0, 0);
            }
            if (kk < 7) {
#pragma unroll
                for (int mi = 0; mi < 4; ++mi)
#pragma unroll
                    for (int kh = 0; kh < 2; ++kh) aC[mi][kh] = aN[mi][kh];
            }
        }

        // epilogue: partial score over this wave's 64 cols (v_b cancels)
#pragma unroll
        for (int mi = 0; mi < 4; ++mi) {
#pragma unroll
            for (int reg = 0; reg < 4; ++reg) {
                const int rl = wM * 64 + mi * 16 + q * 4 + reg;  // 0..255
                const int n = rl & 31;  // rowBase % 256 == 0
                float psum = 0.f;
#pragma unroll
                for (int ni = 0; ni < 4; ++ni) {
                    const int gcol = colBase + wN * 64 + ni * 16 + c;
                    float e = acc[mi][ni][reg] + bias_t[gcol * Ndim + n];
                    psum += vcol[ni] * ftanh(e);
                }
                psum += __shfl_xor(psum, 1);
                psum += __shfl_xor(psum, 2);
                psum += __shfl_xor(psum, 4);
                psum += __shfl_xor(psum, 8);
                if (c == 0) ssm[wN][rl] = psum;
            }
        }
        __syncthreads();
        if (t < 256) {
            const int m = rowBase + t;
            scorep[strip * Mdim + (m & 31) * Sdim + (m >> 5)] =
                ssm[0][t] + ssm[1][t];
        }
        __syncthreads();  // protect ssm for next panel
    }
}

// ---------------- softmax over S per n; sums 4 strip partials;
// writes wts [N][S] (coalesced) AND out_w [S][N] (output layout).
__global__ __launch_bounds__(256) void k_softmax(
    const float* __restrict__ scorep, float* __restrict__ wts,
    float* __restrict__ out_w) {
    const int n = blockIdx.x;
    const int t = threadIdx.x;
    const int w = t >> 6;
    __shared__ float row[Sdim];
    __shared__ float red[8];
    const float4* s0 = (const float4*)(scorep + n * Sdim);
    const float4* s1 = (const float4*)(scorep + Mdim + n * Sdim);
    const float4* s2 = (const float4*)(scorep + 2 * Mdim + n * Sdim);
    const float4* s3 = (const float4*)(scorep + 3 * Mdim + n * Sdim);
    float mx = -1e30f;
    for (int i = t; i < Sdim / 4; i += 256) {
        float4 a = s0[i], b = s1[i], cc = s2[i], d = s3[i];
        float4 v;
        v.x = a.x + b.x + cc.x + d.x; v.y = a.y + b.y + cc.y + d.y;
        v.z = a.z + b.z + cc.z + d.z; v.w = a.w + b.w + cc.w + d.w;
        ((float4*)row)[i] = v;
        mx = fmaxf(mx, fmaxf(fmaxf(v.x, v.y), fmaxf(v.z, v.w)));
    }
#pragma unroll
    for (int o = 32; o > 0; o >>= 1) mx = fmaxf(mx, __shfl_xor(mx, o));
    if ((t & 63) == 0) red[w] = mx;
    __syncthreads();
    mx = fmaxf(fmaxf(red[0], red[1]), fmaxf(red[2], red[3]));
    float sum = 0.f;
    for (int i = t; i < Sdim; i += 256) sum += __expf(row[i] - mx);
#pragma unroll
    for (int o = 32; o > 0; o >>= 1) sum += __shfl_xor(sum, o);
    if ((t & 63) == 0) red[4 + w] = sum;
    __syncthreads();
    sum = red[4] + red[5] + red[6] + red[7];
    const float inv = 1.f / sum;
    for (int i = t; i < Sdim; i += 256) {
        const float wv = __expf(row[i] - mx) * inv;
        wts[n * Sdim + i] = wv;
        out_w[(size_t)i * Ndim + n] = wv;
    }
}

// ---------------- context partials over 128-s chunks
__global__ __launch_bounds__(256) void k_context(
    const float* __restrict__ enc, const float* __restrict__ wts,  // [N][S]
    float* __restrict__ part) {
    const int n = blockIdx.x & 31;
    const int sc = blockIdx.x >> 5;  // 0..31
    const int s0 = sc * 128;
    const int t = threadIdx.x;
    const int hv = t & 127;
    const int sl = t >> 7;
    const float* wrow = wts + (size_t)n * Sdim + s0;
    float4 a0 = {0, 0, 0, 0}, a1 = {0, 0, 0, 0};
    float4 a2 = {0, 0, 0, 0}, a3 = {0, 0, 0, 0};
    for (int i = sl * 4; i < 128; i += 8) {
        const float w0 = wrow[i], w1 = wrow[i + 1];
        const float w2 = wrow[i + 2], w3 = wrow[i + 3];
        const float4 e0 = *(const float4*)(enc + ((size_t)(s0 + i) * Ndim + n) * Hdim + hv * 4);
        const float4 e1 = *(const float4*)(enc + ((size_t)(s0 + i + 1) * Ndim + n) * Hdim + hv * 4);
        const float4 e2 = *(const float4*)(enc + ((size_t)(s0 + i + 2) * Ndim + n) * Hdim + hv * 4);
        const float4 e3 = *(const float4*)(enc + ((size_t)(s0 + i + 3) * Ndim + n) * Hdim + hv * 4);
        a0.x += w0 * e0.x; a0.y += w0 * e0.y; a0.z += w0 * e0.z; a0.w += w0 * e0.w;
        a1.x += w1 * e1.x; a1.y += w1 * e1.y; a1.z += w1 * e1.z; a1.w += w1 * e1.w;
        a2.x += w2 * e2.x; a2.y += w2 * e2.y; a2.z += w2 * e2.z; a2.w += w2 * e2.w;
        a3.x += w3 * e3.x; a3.y += w3 * e3.y; a3.z += w3 * e3.z; a3.w += w3 * e3.w;
    }
    a0.x += a1.x + a2.x + a3.x; a0.y += a1.y + a2.y + a3.y;
    a0.z += a1.z + a2.z + a3.z; a0.w += a1.w + a2.w + a3.w;
    __shared__ float4 red[128];
    if (sl == 1) red[hv] = a0;
    __syncthreads();
    if (sl == 0) {
        const float4 b = red[hv];
        float4 r;
        r.x = a0.x + b.x; r.y = a0.y + b.y; r.z = a0.z + b.z; r.w = a0.w + b.w;
        *(float4*)(part + (size_t)(sc * 32 + n) * Hdim + hv * 4) = r;
    }
}

__global__ __launch_bounds__(256) void k_ctx_reduce(
    const float* __restrict__ part, float* __restrict__ out) {
    const int j = blockIdx.x * 256 + threadIdx.x;
    float4 s = {0, 0, 0, 0};
    for (int i = 0; i < 32; ++i) {
        const float4 v = ((const float4*)part)[i * 4096 + j];
        s.x += v.x; s.y += v.y; s.z += v.z; s.w += v.w;
    }
    ((float4*)out)[j] = s;
}

extern "C" void kernel_launch(void* const* d_in, const int* in_sizes, int n_in,
                              void* d_out, int out_size, void* d_ws,
                              size_t ws_size, hipStream_t stream) {
    const float* hidden = (const float*)d_in[0];
    const float* enc    = (const float*)d_in[1];
    const float* Ww     = (const float*)d_in[2];
    const float* Wb     = (const float*)d_in[3];
    const float* Uw     = (const float*)d_in[4];
    const float* Ubias  = (const float*)d_in[5];
    const float* vw     = (const float*)d_in[6];

    float* out = (float*)d_out;  // [0,16384): context; rest: weights [S][N]

    char* ws = (char*)d_ws;
    unsigned short* Ub16 = (unsigned short*)(ws);              // 512 KB
    float* bias_t        = (float*)(ws + (512 << 10));         // 64 KB
    float* scorep        = (float*)(ws + (576 << 10));         // 2 MB (4 strips)
    float* wts           = (float*)(ws + (2624 << 10));        // 512 KB
    float* part          = (float*)(ws + (3136 << 10));        // 2 MB
    unsigned short* encb = (unsigned short*)(ws + (8 << 20));  // 128 MB

    (void)hipFuncSetAttribute((const void*)k_gemm_score,
                              hipFuncAttributeMaxDynamicSharedMemorySize,
                              131072);

    k_prep<<<384, 256, 0, stream>>>(hidden, Ww, Wb, Ubias, Uw, bias_t, Ub16);
    k_cvt_enc<<<32768, 256, 0, stream>>>(enc, encb);
    k_gemm_score<<<512, 512, 131072, stream>>>(encb, Ub16, bias_t, vw, scorep);
    k_softmax<<<Ndim, 256, 0, stream>>>(scorep, wts, out + Ndim * Hdim);
    k_context<<<Ndim * (Sdim / 128), 256, 0, stream>>>(enc, wts, part);
    k_ctx_reduce<<<16, 256, 0, stream>>>(part, out);
}